// Round 1
// baseline (221.458 us; speedup 1.0000x reference)
//
#include <hip/hip_runtime.h>

#define T_SEQ 4096
#define BATCH 4
#define DD 128
#define BT (BATCH * T_SEQ)

typedef __bf16 bf16x8 __attribute__((ext_vector_type(8)));
typedef float f32x4 __attribute__((ext_vector_type(4)));

__device__ inline bf16x8 ld8(const unsigned short* p) {
  return *reinterpret_cast<const bf16x8*>(p);
}
__device__ inline unsigned short bfc(float f) {
  __bf16 v = (__bf16)f;
  return __builtin_bit_cast(unsigned short, v);
}
__device__ inline float fexp2(float x) {
  float r;
  asm("v_exp_f32 %0, %1" : "=v"(r) : "v"(x));
  return r;
}

#define MFMA(a, b, c) __builtin_amdgcn_mfma_f32_16x16x32_bf16((a), (b), (c), 0, 0, 0)

// ---- W (128x128 f32, [d][u]) -> frag-major bf16:
// F[((n0*4+c)*64 + lane)*8 + j] = W[(c*32+g*8+j)*128 + n0*16+t], lane=(g<<4)|t.
__global__ void wt_kernel(const float* __restrict__ Wq, const float* __restrict__ Wk,
                          const float* __restrict__ Wv,
                          unsigned short* __restrict__ fq, unsigned short* __restrict__ fk,
                          unsigned short* __restrict__ fv) {
  const float* W = (blockIdx.y == 0) ? Wq : (blockIdx.y == 1) ? Wk : Wv;
  unsigned short* F = (blockIdx.y == 0) ? fq : (blockIdx.y == 1) ? fk : fv;
  int e = blockIdx.x * 256 + threadIdx.x;          // 0..16383
  int j = e & 7, lane = (e >> 3) & 63, nc = e >> 9;
  int c = nc & 3, n0 = nc >> 2;
  int t = lane & 15, g = lane >> 4;
  F[e] = bfc(W[(c * 32 + g * 8 + j) * 128 + n0 * 16 + t]);
}

// ---- projections, W-STATIONARY: wave w keeps W-frags for strips {w, w+4} in
// registers (24 KB loaded once/block) and streams 32 X-rows via LDS.
// qf folds (1/sqrt(4096)) * log2(e) so attn can use raw v_exp_f32 (2^x).
__global__ __launch_bounds__(256) void proj_kernel(
    const float* __restrict__ X,
    const unsigned short* __restrict__ fq,
    const unsigned short* __restrict__ fk,
    const unsigned short* __restrict__ fv,
    unsigned short* __restrict__ qf,
    unsigned short* __restrict__ kf,
    unsigned short* __restrict__ vt) {
  const int tid = threadIdx.x;
  const int w = tid >> 6, lane = tid & 63;
  const int t = lane & 15, g = lane >> 4;
  const int r0 = blockIdx.x * 32;   // 512 blocks x 32 rows

  __shared__ unsigned short xs[2][16 * 136];

  // resident W fragments: strips n0/u0 in {w, w+4}
  bf16x8 wq[2][4], wk[2][4], wv[2][4];
#pragma unroll
  for (int s = 0; s < 2; ++s)
#pragma unroll
    for (int c = 0; c < 4; ++c) {
      int fo = (((w + s * 4) * 4 + c) * 64 + lane) * 8;
      wq[s][c] = ld8(fq + fo);
      wk[s][c] = ld8(fk + fo);
      wv[s][c] = ld8(fv + fo);
    }

  // stage both 16-row X subtiles, coalesced
#pragma unroll
  for (int sub = 0; sub < 2; ++sub) {
    int r = tid >> 4, cb = tid & 15;
    const float* xp = X + (size_t)(r0 + sub * 16 + r) * DD + cb * 8;
    float4 lo = *reinterpret_cast<const float4*>(xp);
    float4 hi = *reinterpret_cast<const float4*>(xp + 4);
    bf16x8 tmp;
    tmp[0] = (__bf16)lo.x; tmp[1] = (__bf16)lo.y; tmp[2] = (__bf16)lo.z; tmp[3] = (__bf16)lo.w;
    tmp[4] = (__bf16)hi.x; tmp[5] = (__bf16)hi.y; tmp[6] = (__bf16)hi.z; tmp[7] = (__bf16)hi.w;
    *reinterpret_cast<bf16x8*>(&xs[sub][r * 136 + cb * 8]) = tmp;
  }
  __syncthreads();

#pragma unroll
  for (int sub = 0; sub < 2; ++sub) {
    const int r0s = r0 + sub * 16;
    bf16x8 x[4];
#pragma unroll
    for (int c = 0; c < 4; ++c)
      x[c] = ld8(&xs[sub][t * 136 + c * 32 + g * 8]);

    // Q, K strips
#pragma unroll
    for (int s = 0; s < 2; ++s) {
      const int n0 = w + s * 4;
      f32x4 aq = {0.f, 0.f, 0.f, 0.f}, ak = {0.f, 0.f, 0.f, 0.f};
#pragma unroll
      for (int c = 0; c < 4; ++c) {
        aq = MFMA(x[c], wq[s][c], aq);
        ak = MFMA(x[c], wk[s][c], ak);
      }
      const int cP = n0 >> 1;
      const int Gp = ((n0 & 1) << 1) | (t >> 3);
      const int ep = t & 7;
#pragma unroll
      for (int r = 0; r < 4; ++r) {
        int row = r0s + g * 4 + r;
        size_t qoff = ((size_t)((row >> 4) * 4 + cP) * 64 + ((Gp << 4) | (row & 15))) * 8 + ep;
        qf[qoff] = bfc(aq[r] * 0.0225421101f);   // (1/64) * log2(e)
        int tp = (row & 3) | (((row >> 3) & 3) << 2);
        size_t koff =
            ((size_t)(((row >> 5) * 2 + ((row >> 2) & 1)) * 4 + cP) * 64 + ((Gp << 4) | tp)) * 8 +
            ep;
        kf[koff] = bfc(ak[r]);
      }
    }

    // V strips (k-blocked V^T store)
    const int key = r0s + t;
    const size_t vbase = (size_t)(key >> 5) * 4096 + (key & 31);
#pragma unroll
    for (int s = 0; s < 2; ++s) {
      const int u0 = w + s * 4;
      f32x4 av = {0.f, 0.f, 0.f, 0.f};
#pragma unroll
      for (int c = 0; c < 4; ++c)
        av = MFMA(wv[s][c], x[c], av);
#pragma unroll
      for (int r = 0; r < 4; ++r)
        vt[vbase + (size_t)(u0 * 16 + g * 4 + r) * 32] = bfc(av[r]);
    }
  }
}

// ---- flash attention, flattened: the causal triangle is split into 4352
// uniform wave-tasks (32 queries x <=8 key-chunks each). One task per wave,
// 1088 blocks x 4 waves, no LDS -> 16 waves/CU. Since there is no online max
// (|s| small), partial (O, l) from disjoint key ranges ADD: each wave
// atomicAdds its partial into out/Lp; norm_kernel divides at the end.
// Per batch: sigma-octet m (sigma in [8m,8m+7]) has m+1 groups of 8 chunks;
// task count = 8 * sum(m+1) = 1088. Big-sigma tasks get low block indices
// (dispatch first); the 64 blocks beyond the 1024 resident slots are tiny.
// l is accumulated by an extra MFMA against a ones-fragment, which lands it
// already aligned with O's row mapping (no shuffles).
__global__ __launch_bounds__(256, 4) void attn_kernel(
    const unsigned short* __restrict__ qf,
    const unsigned short* __restrict__ kf,
    const unsigned short* __restrict__ vt,
    float* __restrict__ Lp,
    float* __restrict__ out) {
  const int tid = threadIdx.x;
  const int lane = tid & 63;
  const int t = lane & 15, G = lane >> 4;
  const int bi = blockIdx.x;
  const int xcd = bi & 7;                       // assumed round-robin XCD mapping
  const int b = xcd >> 1;                       // batch pinned to an XCD pair (L2)
  const int idx = ((bi >> 3) << 1) | (xcd & 1); // 0..271 within batch
  int tw = 1087 - (idx * 4 + (tid >> 6));       // biggest tasks dispatch first
  tw = __builtin_amdgcn_readfirstlane(tw);
  // decode task -> (sigma, chunk-group)
  int m = 0;
  while (tw >= 4 * (m + 1) * (m + 2)) ++m;
  const int off = tw - 4 * m * (m + 1);
  const int sig = __builtin_amdgcn_readfirstlane(8 * m + off / (m + 1));
  const int g = __builtin_amdgcn_readfirstlane(off % (m + 1));
  const int q0 = sig * 32;
  const int jbeg = g * 8;
  const int jend = min(jbeg + 8, sig + 1);

  const unsigned short* kfb = kf + (size_t)b * (T_SEQ * DD);
  const unsigned short* vtb = vt + (size_t)b * (T_SEQ * DD);

  // Q fragments for tiles 2*sig, 2*sig+1
  bf16x8 qa[2][4];
#pragma unroll
  for (int p = 0; p < 2; ++p)
#pragma unroll
    for (int c = 0; c < 4; ++c)
      qa[p][c] = ld8(qf + ((size_t)((b * 256 + 2 * sig + p) * 4 + c) * 64 + lane) * 8);

  bf16x8 ones;
#pragma unroll
  for (int e = 0; e < 8; ++e) ones[e] = (__bf16)1.0f;

  f32x4 O[2][8];
#pragma unroll
  for (int p = 0; p < 2; ++p)
#pragma unroll
    for (int u0 = 0; u0 < 8; ++u0) O[p][u0] = (f32x4){0.f, 0.f, 0.f, 0.f};
  f32x4 lv0 = {0.f, 0.f, 0.f, 0.f}, lv1 = {0.f, 0.f, 0.f, 0.f};

  for (int j = jbeg; j < jend; ++j) {
    const unsigned short* kblk = kfb + (size_t)j * 4096;
    const unsigned short* vblk = vtb + (size_t)j * 4096;
    bf16x8 kc[8], vc[8];
#pragma unroll
    for (int ci = 0; ci < 8; ++ci) kc[ci] = ld8(kblk + ci * 512 + lane * 8);
#pragma unroll
    for (int u0 = 0; u0 < 8; ++u0) vc[u0] = ld8(vblk + (u0 * 16 + t) * 32 + G * 8);

    f32x4 s00 = {0.f, 0.f, 0.f, 0.f}, s01 = {0.f, 0.f, 0.f, 0.f};
    f32x4 s10 = {0.f, 0.f, 0.f, 0.f}, s11 = {0.f, 0.f, 0.f, 0.f};
#pragma unroll
    for (int c = 0; c < 4; ++c) {
      s00 = MFMA(kc[c], qa[0][c], s00);
      s01 = MFMA(kc[4 + c], qa[0][c], s01);
      s10 = MFMA(kc[c], qa[1][c], s10);
      s11 = MFMA(kc[4 + c], qa[1][c], s11);
    }

    bf16x8 pb0, pb1;
    if (j < sig) {
      // fully-unmasked chunk (all but the diagonal): no causal compares
#pragma unroll
      for (int r = 0; r < 4; ++r) {
        pb0[r]     = (__bf16)fexp2(s00[r]);
        pb0[r + 4] = (__bf16)fexp2(s01[r]);
        pb1[r]     = (__bf16)fexp2(s10[r]);
        pb1[r + 4] = (__bf16)fexp2(s11[r]);
      }
    } else {
#pragma unroll
      for (int r = 0; r < 4; ++r) {
        int k0 = j * 32 + G * 8 + r;
        float e00 = (k0 <= q0 + t) ? fexp2(s00[r]) : 0.f;
        float e01 = (k0 + 4 <= q0 + t) ? fexp2(s01[r]) : 0.f;
        float e10 = (k0 <= q0 + 16 + t) ? fexp2(s10[r]) : 0.f;
        float e11 = (k0 + 4 <= q0 + 16 + t) ? fexp2(s11[r]) : 0.f;
        pb0[r] = (__bf16)e00; pb0[r + 4] = (__bf16)e01;
        pb1[r] = (__bf16)e10; pb1[r + 4] = (__bf16)e11;
      }
    }

    lv0 = MFMA(pb0, ones, lv0);   // row-sums on the MFMA pipe, O-row-aligned
    lv1 = MFMA(pb1, ones, lv1);
#pragma unroll
    for (int u0 = 0; u0 < 8; ++u0) {
      O[0][u0] = MFMA(pb0, vc[u0], O[0][u0]);
      O[1][u0] = MFMA(pb1, vc[u0], O[1][u0]);
    }
  }

  // lv[r] is replicated across t; only t==0 lanes contribute
  if (t == 0) {
#pragma unroll
    for (int r = 0; r < 4; ++r) {
      atomicAdd(&Lp[b * T_SEQ + q0 + G * 4 + r], lv0[r]);
      atomicAdd(&Lp[b * T_SEQ + q0 + 16 + G * 4 + r], lv1[r]);
    }
  }
  // O[p][u0][r] = partial Out[query q0+16p+G*4+r][u0*16+t]
  float* ob = out + ((size_t)(b * T_SEQ + q0 + G * 4)) * DD + t;
#pragma unroll
  for (int u0 = 0; u0 < 8; ++u0)
#pragma unroll
    for (int r = 0; r < 4; ++r) {
      atomicAdd(ob + (size_t)r * DD + u0 * 16, O[0][u0][r]);
      atomicAdd(ob + (size_t)(16 + r) * DD + u0 * 16, O[1][u0][r]);
    }
}

// ---- final softmax normalization: out[q][u] /= Lp[q]
__global__ __launch_bounds__(256) void norm_kernel(float* __restrict__ out,
                                                   const float* __restrict__ Lp) {
  const int i = blockIdx.x * 256 + threadIdx.x;   // one float4 per thread
  float4 v = reinterpret_cast<float4*>(out)[i];
  const float linv = 1.0f / Lp[i >> 5];           // 32 float4 per 128-wide row
  v.x *= linv; v.y *= linv; v.z *= linv; v.w *= linv;
  reinterpret_cast<float4*>(out)[i] = v;
}

extern "C" void kernel_launch(void* const* d_in, const int* in_sizes, int n_in,
                              void* d_out, int out_size, void* d_ws, size_t ws_size,
                              hipStream_t stream) {
  const float* X  = (const float*)d_in[0];
  const float* Wq = (const float*)d_in[1];
  const float* Wk = (const float*)d_in[2];
  const float* Wv = (const float*)d_in[3];
  float* out = (float*)d_out;

  unsigned short* qf = (unsigned short*)d_ws;          // frag-major Q [BT/16][4][64][8]
  unsigned short* kf = qf + (size_t)BT * DD;            // frag-major K [BT/32][2][4][64][8]
  unsigned short* vt = kf + (size_t)BT * DD;            // k-blocked V^T [BT/32][128][32]
  unsigned short* fq = vt + (size_t)BT * DD;            // frag-major W (16384 each)
  unsigned short* fk = fq + DD * DD;
  unsigned short* fv = fk + DD * DD;
  float* Lp = (float*)(fv + DD * DD);                   // exp-sums [BATCH][T_SEQ]

  // out/Lp are atomic accumulators: zero them each launch (graph-capturable)
  hipMemsetAsync(d_out, 0, (size_t)BT * DD * sizeof(float), stream);
  hipMemsetAsync(Lp, 0, (size_t)BT * sizeof(float), stream);

  dim3 wt_grid(64, 3);
  wt_kernel<<<wt_grid, 256, 0, stream>>>(Wq, Wk, Wv, fq, fk, fv);
  proj_kernel<<<BT / 32, 256, 0, stream>>>(X, fq, fk, fv, qf, kf, vt);
  attn_kernel<<<1088, 256, 0, stream>>>(qf, kf, vt, Lp, out);
  norm_kernel<<<(BT * DD / 4) / 256, 256, 0, stream>>>(out, Lp);
}

// Round 3
// 170.252 us; speedup vs baseline: 1.3008x; 1.3008x over previous
//
#include <hip/hip_runtime.h>

#define T_SEQ 4096
#define BATCH 4
#define DD 128
#define BT (BATCH * T_SEQ)

typedef __bf16 bf16x8 __attribute__((ext_vector_type(8)));
typedef float f32x4 __attribute__((ext_vector_type(4)));

__device__ inline bf16x8 ld8(const unsigned short* p) {
  return *reinterpret_cast<const bf16x8*>(p);
}
__device__ inline unsigned short bfc(float f) {
  __bf16 v = (__bf16)f;
  return __builtin_bit_cast(unsigned short, v);
}
__device__ inline float fexp2(float x) {
  float r;
  asm("v_exp_f32 %0, %1" : "=v"(r) : "v"(x));
  return r;
}

#define MFMA(a, b, c) __builtin_amdgcn_mfma_f32_16x16x32_bf16((a), (b), (c), 0, 0, 0)

// ---- W (128x128 f32, [d][u]) -> frag-major bf16:
// F[((n0*4+c)*64 + lane)*8 + j] = W[(c*32+g*8+j)*128 + n0*16+t], lane=(g<<4)|t.
__global__ void wt_kernel(const float* __restrict__ Wq, const float* __restrict__ Wk,
                          const float* __restrict__ Wv,
                          unsigned short* __restrict__ fq, unsigned short* __restrict__ fk,
                          unsigned short* __restrict__ fv) {
  const float* W = (blockIdx.y == 0) ? Wq : (blockIdx.y == 1) ? Wk : Wv;
  unsigned short* F = (blockIdx.y == 0) ? fq : (blockIdx.y == 1) ? fk : fv;
  int e = blockIdx.x * 256 + threadIdx.x;          // 0..16383
  int j = e & 7, lane = (e >> 3) & 63, nc = e >> 9;
  int c = nc & 3, n0 = nc >> 2;
  int t = lane & 15, g = lane >> 4;
  F[e] = bfc(W[(c * 32 + g * 8 + j) * 128 + n0 * 16 + t]);
}

// ---- projections, W-STATIONARY: wave w keeps W-frags for strips {w, w+4} in
// registers (24 KB loaded once/block) and streams 32 X-rows via LDS.
// qf folds (1/sqrt(4096)) * log2(e) so attn can use raw v_exp_f32 (2^x).
__global__ __launch_bounds__(256) void proj_kernel(
    const float* __restrict__ X,
    const unsigned short* __restrict__ fq,
    const unsigned short* __restrict__ fk,
    const unsigned short* __restrict__ fv,
    unsigned short* __restrict__ qf,
    unsigned short* __restrict__ kf,
    unsigned short* __restrict__ vt) {
  const int tid = threadIdx.x;
  const int w = tid >> 6, lane = tid & 63;
  const int t = lane & 15, g = lane >> 4;
  const int r0 = blockIdx.x * 32;   // 512 blocks x 32 rows

  __shared__ unsigned short xs[2][16 * 136];

  // resident W fragments: strips n0/u0 in {w, w+4}
  bf16x8 wq[2][4], wk[2][4], wv[2][4];
#pragma unroll
  for (int s = 0; s < 2; ++s)
#pragma unroll
    for (int c = 0; c < 4; ++c) {
      int fo = (((w + s * 4) * 4 + c) * 64 + lane) * 8;
      wq[s][c] = ld8(fq + fo);
      wk[s][c] = ld8(fk + fo);
      wv[s][c] = ld8(fv + fo);
    }

  // stage both 16-row X subtiles, coalesced
#pragma unroll
  for (int sub = 0; sub < 2; ++sub) {
    int r = tid >> 4, cb = tid & 15;
    const float* xp = X + (size_t)(r0 + sub * 16 + r) * DD + cb * 8;
    float4 lo = *reinterpret_cast<const float4*>(xp);
    float4 hi = *reinterpret_cast<const float4*>(xp + 4);
    bf16x8 tmp;
    tmp[0] = (__bf16)lo.x; tmp[1] = (__bf16)lo.y; tmp[2] = (__bf16)lo.z; tmp[3] = (__bf16)lo.w;
    tmp[4] = (__bf16)hi.x; tmp[5] = (__bf16)hi.y; tmp[6] = (__bf16)hi.z; tmp[7] = (__bf16)hi.w;
    *reinterpret_cast<bf16x8*>(&xs[sub][r * 136 + cb * 8]) = tmp;
  }
  __syncthreads();

#pragma unroll
  for (int sub = 0; sub < 2; ++sub) {
    const int r0s = r0 + sub * 16;
    bf16x8 x[4];
#pragma unroll
    for (int c = 0; c < 4; ++c)
      x[c] = ld8(&xs[sub][t * 136 + c * 32 + g * 8]);

    // Q, K strips
#pragma unroll
    for (int s = 0; s < 2; ++s) {
      const int n0 = w + s * 4;
      f32x4 aq = {0.f, 0.f, 0.f, 0.f}, ak = {0.f, 0.f, 0.f, 0.f};
#pragma unroll
      for (int c = 0; c < 4; ++c) {
        aq = MFMA(x[c], wq[s][c], aq);
        ak = MFMA(x[c], wk[s][c], ak);
      }
      const int cP = n0 >> 1;
      const int Gp = ((n0 & 1) << 1) | (t >> 3);
      const int ep = t & 7;
#pragma unroll
      for (int r = 0; r < 4; ++r) {
        int row = r0s + g * 4 + r;
        size_t qoff = ((size_t)((row >> 4) * 4 + cP) * 64 + ((Gp << 4) | (row & 15))) * 8 + ep;
        qf[qoff] = bfc(aq[r] * 0.0225421101f);   // (1/64) * log2(e)
        int tp = (row & 3) | (((row >> 3) & 3) << 2);
        size_t koff =
            ((size_t)(((row >> 5) * 2 + ((row >> 2) & 1)) * 4 + cP) * 64 + ((Gp << 4) | tp)) * 8 +
            ep;
        kf[koff] = bfc(ak[r]);
      }
    }

    // V strips (k-blocked V^T store)
    const int key = r0s + t;
    const size_t vbase = (size_t)(key >> 5) * 4096 + (key & 31);
#pragma unroll
    for (int s = 0; s < 2; ++s) {
      const int u0 = w + s * 4;
      f32x4 av = {0.f, 0.f, 0.f, 0.f};
#pragma unroll
      for (int c = 0; c < 4; ++c)
        av = MFMA(wv[s][c], x[c], av);
#pragma unroll
      for (int r = 0; r < 4; ++r)
        vt[vbase + (size_t)(u0 * 16 + g * 4 + r) * 32] = bfc(av[r]);
    }
  }
}

// ---- flash attention: 32 queries/wave (2 q-tiles share every K/V load),
// 8-way key split per block (512 threads / 8 waves -> 4096 waves total =
// 4 waves/SIMD, 2 blocks/CU), LDS tree combine (no atomics). Balanced sigma
// pairing: blocks bi and bi+256 co-reside on a CU (same XCD via bi&7, same
// slot via (bi>>3)+-32); sigma = 2*wi / 127-2*(wi-64) makes each CU's pair
// sum to exactly 129 chunks. Batch pinned to an XCD pair for K/V L2 locality.
// No explicit register prefetch: under the 128-VGPR cap the allocator cannot
// keep a next-chunk buffer live; latency hiding comes from the 4-wave TLP.
__global__ __launch_bounds__(512, 4) void attn_kernel(
    const unsigned short* __restrict__ qf,
    const unsigned short* __restrict__ kf,
    const unsigned short* __restrict__ vt,
    float* __restrict__ out) {
  const int tid = threadIdx.x;
  const int w = tid >> 6, lane = tid & 63;     // w in [0,8)
  const int t = lane & 15, G = lane >> 4;
  const int bi = blockIdx.x;
  const int xcd = bi & 7;                      // assumed round-robin XCD mapping
  const int b = xcd >> 1;                      // batch pinned to an XCD pair
  const int wi = ((bi >> 3) << 1) | (xcd & 1); // 0..127 within batch
  const int sig = (wi < 64) ? (2 * wi) : (127 - 2 * (wi - 64));  // balanced pairs
  const int q0 = sig * 32;
  const int nch = sig + 1;                     // 32-key chunks

  const unsigned short* kfb = kf + (size_t)b * (T_SEQ * DD);
  const unsigned short* vtb = vt + (size_t)b * (T_SEQ * DD);

  // Q fragments for tiles 2*sig, 2*sig+1: coalesced 1-KB loads
  bf16x8 qa[2][4];
#pragma unroll
  for (int p = 0; p < 2; ++p)
#pragma unroll
    for (int c = 0; c < 4; ++c)
      qa[p][c] = ld8(qf + ((size_t)((b * 256 + 2 * sig + p) * 4 + c) * 64 + lane) * 8);

  f32x4 O[2][8];
#pragma unroll
  for (int p = 0; p < 2; ++p)
#pragma unroll
    for (int u0 = 0; u0 < 8; ++u0) O[p][u0] = (f32x4){0.f, 0.f, 0.f, 0.f};
  float ls0 = 0.f, ls1 = 0.f;

  for (int j = w; j < nch; j += 8) {
    const unsigned short* kblk = kfb + (size_t)j * 4096;
    const unsigned short* vblk = vtb + (size_t)j * 4096;
    bf16x8 kc[8], vc[8];
#pragma unroll
    for (int ci = 0; ci < 8; ++ci) kc[ci] = ld8(kblk + ci * 512 + lane * 8);
#pragma unroll
    for (int u0 = 0; u0 < 8; ++u0) vc[u0] = ld8(vblk + (u0 * 16 + t) * 32 + G * 8);

    f32x4 s00 = {0.f, 0.f, 0.f, 0.f}, s01 = {0.f, 0.f, 0.f, 0.f};
    f32x4 s10 = {0.f, 0.f, 0.f, 0.f}, s11 = {0.f, 0.f, 0.f, 0.f};
#pragma unroll
    for (int c = 0; c < 4; ++c) {
      s00 = MFMA(kc[c], qa[0][c], s00);
      s01 = MFMA(kc[4 + c], qa[0][c], s01);
      s10 = MFMA(kc[c], qa[1][c], s10);
      s11 = MFMA(kc[4 + c], qa[1][c], s11);
    }

    bf16x8 pb0, pb1;
    if (j < sig) {
      // fully-unmasked chunk (all but the diagonal): no causal compares
#pragma unroll
      for (int r = 0; r < 4; ++r) {
        float e00 = fexp2(s00[r]), e01 = fexp2(s01[r]);
        float e10 = fexp2(s10[r]), e11 = fexp2(s11[r]);
        ls0 += e00 + e01;
        ls1 += e10 + e11;
        pb0[r] = (__bf16)e00; pb0[r + 4] = (__bf16)e01;
        pb1[r] = (__bf16)e10; pb1[r + 4] = (__bf16)e11;
      }
    } else {
#pragma unroll
      for (int r = 0; r < 4; ++r) {
        int k0 = j * 32 + G * 8 + r;
        float e00 = (k0 <= q0 + t) ? fexp2(s00[r]) : 0.f;
        float e01 = (k0 + 4 <= q0 + t) ? fexp2(s01[r]) : 0.f;
        float e10 = (k0 <= q0 + 16 + t) ? fexp2(s10[r]) : 0.f;
        float e11 = (k0 + 4 <= q0 + 16 + t) ? fexp2(s11[r]) : 0.f;
        ls0 += e00 + e01;
        ls1 += e10 + e11;
        pb0[r] = (__bf16)e00; pb0[r + 4] = (__bf16)e01;
        pb1[r] = (__bf16)e10; pb1[r + 4] = (__bf16)e11;
      }
    }

#pragma unroll
    for (int u0 = 0; u0 < 8; ++u0) {
      O[0][u0] = MFMA(pb0, vc[u0], O[0][u0]);
      O[1][u0] = MFMA(pb1, vc[u0], O[1][u0]);
    }
  }

  // ---- 8-wave combine via 3-stage LDS tree (3 buffers, same footprint as
  // the proven round-0 path; partials add, no rescale needed)
  __shared__ float cmb[3][64][66];
  auto publish = [&](int buf) {
#pragma unroll
    for (int p = 0; p < 2; ++p)
#pragma unroll
      for (int u0 = 0; u0 < 8; ++u0)
        *reinterpret_cast<f32x4*>(&cmb[buf][lane][p * 32 + u0 * 4]) = O[p][u0];
    cmb[buf][lane][64] = ls0;
    cmb[buf][lane][65] = ls1;
  };
  auto absorb = [&](int buf) {
#pragma unroll
    for (int p = 0; p < 2; ++p)
#pragma unroll
      for (int u0 = 0; u0 < 8; ++u0) {
        f32x4 q4 = *reinterpret_cast<const f32x4*>(&cmb[buf][lane][p * 32 + u0 * 4]);
        O[p][u0][0] += q4[0]; O[p][u0][1] += q4[1];
        O[p][u0][2] += q4[2]; O[p][u0][3] += q4[3];
      }
    ls0 += cmb[buf][lane][64];
    ls1 += cmb[buf][lane][65];
  };
  // stage A: waves 4,5,6 publish; 0,1,2 absorb  -> owners {0+4, 1+5, 2+6, 3, 7}
  if (w >= 4 && w < 7) publish(w - 4);
  __syncthreads();
  if (w < 3) absorb(w);
  __syncthreads();
  // stage B: waves 7 and 3 publish; 0 and 1 absorb -> owners {0+4+7, 1+5+3, 2+6}
  if (w == 7) publish(0);
  if (w == 3) publish(1);
  __syncthreads();
  if (w == 0) absorb(0);
  if (w == 1) absorb(1);
  __syncthreads();
  // stage C: waves 1 and 2 publish; 0 absorbs all
  if (w == 1) publish(0);
  if (w == 2) publish(1);
  __syncthreads();

  if (w == 0) {
    absorb(0);
    absorb(1);
    // row sums: lanes {t,t+16,t+32,t+48} hold partials for query t of each tile
    ls0 += __shfl_xor(ls0, 16); ls0 += __shfl_xor(ls0, 32);
    ls1 += __shfl_xor(ls1, 16); ls1 += __shfl_xor(ls1, 32);
    float linv0[4], linv1[4];
#pragma unroll
    for (int r = 0; r < 4; ++r) {
      linv0[r] = 1.0f / __shfl(ls0, G * 4 + r);
      linv1[r] = 1.0f / __shfl(ls1, G * 4 + r);
    }
    // O[p][u0][r] = Out[query q0+16p+G*4+r][u0*16+t]
    float* op0 = out + ((size_t)(b * T_SEQ + q0 + G * 4)) * DD + t;
    float* op1 = op0 + (size_t)16 * DD;
#pragma unroll
    for (int u0 = 0; u0 < 8; ++u0) {
#pragma unroll
      for (int r = 0; r < 4; ++r) {
        op0[(size_t)r * DD + u0 * 16] = O[0][u0][r] * linv0[r];
        op1[(size_t)r * DD + u0 * 16] = O[1][u0][r] * linv1[r];
      }
    }
  }
}

extern "C" void kernel_launch(void* const* d_in, const int* in_sizes, int n_in,
                              void* d_out, int out_size, void* d_ws, size_t ws_size,
                              hipStream_t stream) {
  const float* X  = (const float*)d_in[0];
  const float* Wq = (const float*)d_in[1];
  const float* Wk = (const float*)d_in[2];
  const float* Wv = (const float*)d_in[3];
  float* out = (float*)d_out;

  unsigned short* qf = (unsigned short*)d_ws;          // frag-major Q [BT/16][4][64][8]
  unsigned short* kf = qf + (size_t)BT * DD;            // frag-major K [BT/32][2][4][64][8]
  unsigned short* vt = kf + (size_t)BT * DD;            // k-blocked V^T [BT/32][128][32]
  unsigned short* fq = vt + (size_t)BT * DD;            // frag-major W (16384 each)
  unsigned short* fk = fq + DD * DD;
  unsigned short* fv = fk + DD * DD;

  dim3 wt_grid(64, 3);
  wt_kernel<<<wt_grid, 256, 0, stream>>>(Wq, Wk, Wv, fq, fk, fv);
  proj_kernel<<<BT / 32, 256, 0, stream>>>(X, fq, fk, fv, qf, kf, vt);
  attn_kernel<<<512, 512, 0, stream>>>(qf, kf, vt, out);
}

// Round 4
// 145.522 us; speedup vs baseline: 1.5218x; 1.1699x over previous
//
#include <hip/hip_runtime.h>

#define T_SEQ 4096
#define BATCH 4
#define DD 128
#define BT (BATCH * T_SEQ)

typedef __bf16 bf16x8 __attribute__((ext_vector_type(8)));
typedef float f32x4 __attribute__((ext_vector_type(4)));

__device__ inline bf16x8 ld8(const unsigned short* p) {
  return *reinterpret_cast<const bf16x8*>(p);
}
__device__ inline unsigned short bfc(float f) {
  __bf16 v = (__bf16)f;
  return __builtin_bit_cast(unsigned short, v);
}
__device__ inline float fexp2(float x) {
  float r;
  asm("v_exp_f32 %0, %1" : "=v"(r) : "v"(x));
  return r;
}

#define MFMA(a, b, c) __builtin_amdgcn_mfma_f32_16x16x32_bf16((a), (b), (c), 0, 0, 0)

// ---- W (128x128 f32, [d][u]) -> frag-major bf16:
// F[((n0*4+c)*64 + lane)*8 + j] = W[(c*32+g*8+j)*128 + n0*16+t], lane=(g<<4)|t.
__global__ void wt_kernel(const float* __restrict__ Wq, const float* __restrict__ Wk,
                          const float* __restrict__ Wv,
                          unsigned short* __restrict__ fq, unsigned short* __restrict__ fk,
                          unsigned short* __restrict__ fv) {
  const float* W = (blockIdx.y == 0) ? Wq : (blockIdx.y == 1) ? Wk : Wv;
  unsigned short* F = (blockIdx.y == 0) ? fq : (blockIdx.y == 1) ? fk : fv;
  int e = blockIdx.x * 256 + threadIdx.x;          // 0..16383
  int j = e & 7, lane = (e >> 3) & 63, nc = e >> 9;
  int c = nc & 3, n0 = nc >> 2;
  int t = lane & 15, g = lane >> 4;
  F[e] = bfc(W[(c * 32 + g * 8 + j) * 128 + n0 * 16 + t]);
}

// ---- projections, W-STATIONARY: wave w keeps W-frags for strips {w, w+4} in
// registers (24 KB loaded once/block) and streams 32 X-rows via LDS.
// qf folds (1/sqrt(4096)) * log2(e) so attn can use raw v_exp_f32 (2^x).
__global__ __launch_bounds__(256) void proj_kernel(
    const float* __restrict__ X,
    const unsigned short* __restrict__ fq,
    const unsigned short* __restrict__ fk,
    const unsigned short* __restrict__ fv,
    unsigned short* __restrict__ qf,
    unsigned short* __restrict__ kf,
    unsigned short* __restrict__ vt) {
  const int tid = threadIdx.x;
  const int w = tid >> 6, lane = tid & 63;
  const int t = lane & 15, g = lane >> 4;
  const int r0 = blockIdx.x * 32;   // 512 blocks x 32 rows

  __shared__ unsigned short xs[2][16 * 136];

  // resident W fragments: strips n0/u0 in {w, w+4}
  bf16x8 wq[2][4], wk[2][4], wv[2][4];
#pragma unroll
  for (int s = 0; s < 2; ++s)
#pragma unroll
    for (int c = 0; c < 4; ++c) {
      int fo = (((w + s * 4) * 4 + c) * 64 + lane) * 8;
      wq[s][c] = ld8(fq + fo);
      wk[s][c] = ld8(fk + fo);
      wv[s][c] = ld8(fv + fo);
    }

  // stage both 16-row X subtiles, coalesced
#pragma unroll
  for (int sub = 0; sub < 2; ++sub) {
    int r = tid >> 4, cb = tid & 15;
    const float* xp = X + (size_t)(r0 + sub * 16 + r) * DD + cb * 8;
    float4 lo = *reinterpret_cast<const float4*>(xp);
    float4 hi = *reinterpret_cast<const float4*>(xp + 4);
    bf16x8 tmp;
    tmp[0] = (__bf16)lo.x; tmp[1] = (__bf16)lo.y; tmp[2] = (__bf16)lo.z; tmp[3] = (__bf16)lo.w;
    tmp[4] = (__bf16)hi.x; tmp[5] = (__bf16)hi.y; tmp[6] = (__bf16)hi.z; tmp[7] = (__bf16)hi.w;
    *reinterpret_cast<bf16x8*>(&xs[sub][r * 136 + cb * 8]) = tmp;
  }
  __syncthreads();

#pragma unroll
  for (int sub = 0; sub < 2; ++sub) {
    const int r0s = r0 + sub * 16;
    bf16x8 x[4];
#pragma unroll
    for (int c = 0; c < 4; ++c)
      x[c] = ld8(&xs[sub][t * 136 + c * 32 + g * 8]);

    // Q, K strips
#pragma unroll
    for (int s = 0; s < 2; ++s) {
      const int n0 = w + s * 4;
      f32x4 aq = {0.f, 0.f, 0.f, 0.f}, ak = {0.f, 0.f, 0.f, 0.f};
#pragma unroll
      for (int c = 0; c < 4; ++c) {
        aq = MFMA(x[c], wq[s][c], aq);
        ak = MFMA(x[c], wk[s][c], ak);
      }
      const int cP = n0 >> 1;
      const int Gp = ((n0 & 1) << 1) | (t >> 3);
      const int ep = t & 7;
#pragma unroll
      for (int r = 0; r < 4; ++r) {
        int row = r0s + g * 4 + r;
        size_t qoff = ((size_t)((row >> 4) * 4 + cP) * 64 + ((Gp << 4) | (row & 15))) * 8 + ep;
        qf[qoff] = bfc(aq[r] * 0.0225421101f);   // (1/64) * log2(e)
        int tp = (row & 3) | (((row >> 3) & 3) << 2);
        size_t koff =
            ((size_t)(((row >> 5) * 2 + ((row >> 2) & 1)) * 4 + cP) * 64 + ((Gp << 4) | tp)) * 8 +
            ep;
        kf[koff] = bfc(ak[r]);
      }
    }

    // V strips (k-blocked V^T store)
    const int key = r0s + t;
    const size_t vbase = (size_t)(key >> 5) * 4096 + (key & 31);
#pragma unroll
    for (int s = 0; s < 2; ++s) {
      const int u0 = w + s * 4;
      f32x4 av = {0.f, 0.f, 0.f, 0.f};
#pragma unroll
      for (int c = 0; c < 4; ++c)
        av = MFMA(wv[s][c], x[c], av);
#pragma unroll
      for (int r = 0; r < 4; ++r)
        vt[vbase + (size_t)(u0 * 16 + g * 4 + r) * 32] = bfc(av[r]);
    }
  }
}

// ---- flash attention, uniform-work blocks: per batch the causal triangle's
// 8256 32-key chunks are flattened (tile sigma=0..127, chunk j=0..sigma) and
// cut into 192 blocks x EXACTLY 43 chunks (8256 = 192*43). Any 3 co-resident
// blocks give a CU exactly 129 chunks -> balance is dispatch-order-proof.
// 768 blocks x 4 waves at 3 blocks/CU = 3 waves/SIMD. Inner loop is the
// proven round-0 structure (112 VGPR under a relaxed cap; launch_bounds
// (256,3) caps at 170 to stay clear of the cap-128 spill cliff seen in r1/r3).
// Blocks owning a whole tile normalize+store directly; boundary tiles write
// raw partial (O, l) to workspace slots (part index = block - first-block,
// <=4 parts/tile, no flags needed) and comb_kernel finishes them.
__global__ __launch_bounds__(256, 3) void attn_kernel(
    const unsigned short* __restrict__ qf,
    const unsigned short* __restrict__ kf,
    const unsigned short* __restrict__ vt,
    float* __restrict__ pO,
    float* __restrict__ pL,
    float* __restrict__ out) {
  const int tid = threadIdx.x;
  const int w = tid >> 6, lane = tid & 63;
  const int t = lane & 15, G = lane >> 4;
  const int bi = blockIdx.x;
  const int xcd = bi & 7;                      // assumed round-robin XCD mapping
  const int b = xcd >> 1;                      // batch pinned to an XCD pair (L2)
  const int k = ((bi >> 3) << 1) | (xcd & 1);  // 0..191 batch-local block index

  int m = k * 43;                              // global chunk range [m, mend)
  const int mend = m + 43;
  int sig = (int)(0.5f * (sqrtf(8.0f * (float)m + 1.0f) - 1.0f));
  while ((sig + 1) * (sig + 2) / 2 <= m) ++sig;
  while (sig * (sig + 1) / 2 > m) --sig;

  const unsigned short* kfb = kf + (size_t)b * (T_SEQ * DD);
  const unsigned short* vtb = vt + (size_t)b * (T_SEQ * DD);

  __shared__ float cmb[3][64][66];

  while (m < mend) {
    const int tri = sig * (sig + 1) / 2;
    const int j0 = m - tri;
    const int cnt = min(sig + 1 - j0, mend - m);
    const int q0 = sig * 32;

    // Q fragments for tiles 2*sig, 2*sig+1
    bf16x8 qa[2][4];
#pragma unroll
    for (int p = 0; p < 2; ++p)
#pragma unroll
      for (int c = 0; c < 4; ++c)
        qa[p][c] = ld8(qf + ((size_t)((b * 256 + 2 * sig + p) * 4 + c) * 64 + lane) * 8);

    f32x4 O[2][8];
#pragma unroll
    for (int p = 0; p < 2; ++p)
#pragma unroll
      for (int u0 = 0; u0 < 8; ++u0) O[p][u0] = (f32x4){0.f, 0.f, 0.f, 0.f};
    float ls0 = 0.f, ls1 = 0.f;

    for (int j = j0 + w; j < j0 + cnt; j += 4) {
      const unsigned short* kblk = kfb + (size_t)j * 4096;
      const unsigned short* vblk = vtb + (size_t)j * 4096;
      bf16x8 kc[8], vc[8];
#pragma unroll
      for (int ci = 0; ci < 8; ++ci) kc[ci] = ld8(kblk + ci * 512 + lane * 8);
#pragma unroll
      for (int u0 = 0; u0 < 8; ++u0) vc[u0] = ld8(vblk + (u0 * 16 + t) * 32 + G * 8);

      f32x4 s00 = {0.f, 0.f, 0.f, 0.f}, s01 = {0.f, 0.f, 0.f, 0.f};
      f32x4 s10 = {0.f, 0.f, 0.f, 0.f}, s11 = {0.f, 0.f, 0.f, 0.f};
#pragma unroll
      for (int c = 0; c < 4; ++c) {
        s00 = MFMA(kc[c], qa[0][c], s00);
        s01 = MFMA(kc[4 + c], qa[0][c], s01);
        s10 = MFMA(kc[c], qa[1][c], s10);
        s11 = MFMA(kc[4 + c], qa[1][c], s11);
      }

      bf16x8 pb0, pb1;
      if (j < sig) {
        // fully-unmasked chunk (all but the diagonal): no causal compares
#pragma unroll
        for (int r = 0; r < 4; ++r) {
          float e00 = fexp2(s00[r]), e01 = fexp2(s01[r]);
          float e10 = fexp2(s10[r]), e11 = fexp2(s11[r]);
          ls0 += e00 + e01;
          ls1 += e10 + e11;
          pb0[r] = (__bf16)e00; pb0[r + 4] = (__bf16)e01;
          pb1[r] = (__bf16)e10; pb1[r + 4] = (__bf16)e11;
        }
      } else {
#pragma unroll
        for (int r = 0; r < 4; ++r) {
          int k0 = j * 32 + G * 8 + r;
          float e00 = (k0 <= q0 + t) ? fexp2(s00[r]) : 0.f;
          float e01 = (k0 + 4 <= q0 + t) ? fexp2(s01[r]) : 0.f;
          float e10 = (k0 <= q0 + 16 + t) ? fexp2(s10[r]) : 0.f;
          float e11 = (k0 + 4 <= q0 + 16 + t) ? fexp2(s11[r]) : 0.f;
          ls0 += e00 + e01;
          ls1 += e10 + e11;
          pb0[r] = (__bf16)e00; pb0[r + 4] = (__bf16)e01;
          pb1[r] = (__bf16)e10; pb1[r + 4] = (__bf16)e11;
        }
      }

#pragma unroll
      for (int u0 = 0; u0 < 8; ++u0) {
        O[0][u0] = MFMA(pb0, vc[u0], O[0][u0]);
        O[1][u0] = MFMA(pb1, vc[u0], O[1][u0]);
      }
    }

    // ---- single-stage 4-wave LDS combine (round-0 proven path)
    if (w > 0) {
#pragma unroll
      for (int p = 0; p < 2; ++p)
#pragma unroll
        for (int u0 = 0; u0 < 8; ++u0)
          *reinterpret_cast<f32x4*>(&cmb[w - 1][lane][p * 32 + u0 * 4]) = O[p][u0];
      cmb[w - 1][lane][64] = ls0;
      cmb[w - 1][lane][65] = ls1;
    }
    __syncthreads();
    if (w == 0) {
#pragma unroll
      for (int ww = 0; ww < 3; ++ww) {
#pragma unroll
        for (int p = 0; p < 2; ++p)
#pragma unroll
          for (int u0 = 0; u0 < 8; ++u0) {
            f32x4 q4 = *reinterpret_cast<const f32x4*>(&cmb[ww][lane][p * 32 + u0 * 4]);
            O[p][u0][0] += q4[0]; O[p][u0][1] += q4[1];
            O[p][u0][2] += q4[2]; O[p][u0][3] += q4[3];
          }
        ls0 += cmb[ww][lane][64];
        ls1 += cmb[ww][lane][65];
      }
      // row sums over G-groups: afterwards each lane holds the rowsum for
      // query (lane&15) of its tile half
      ls0 += __shfl_xor(ls0, 16); ls0 += __shfl_xor(ls0, 32);
      ls1 += __shfl_xor(ls1, 16); ls1 += __shfl_xor(ls1, 32);

      if (j0 == 0 && cnt == sig + 1) {
        // whole tile in this block: normalize and store directly
        float linv0[4], linv1[4];
#pragma unroll
        for (int r = 0; r < 4; ++r) {
          linv0[r] = 1.0f / __shfl(ls0, G * 4 + r);
          linv1[r] = 1.0f / __shfl(ls1, G * 4 + r);
        }
        float* op0 = out + ((size_t)(b * T_SEQ + q0 + G * 4)) * DD + t;
        float* op1 = op0 + (size_t)16 * DD;
#pragma unroll
        for (int u0 = 0; u0 < 8; ++u0) {
#pragma unroll
          for (int r = 0; r < 4; ++r) {
            op0[(size_t)r * DD + u0 * 16] = O[0][u0][r] * linv0[r];
            op1[(size_t)r * DD + u0 * 16] = O[1][u0][r] * linv1[r];
          }
        }
      } else {
        // partial: raw sums to workspace slot (part = k - first block of tile)
        const int part = k - tri / 43;
        const int slot = (b * 128 + sig) * 4 + part;
        if (lane < 16) {
          pL[slot * 32 + lane] = ls0;
          pL[slot * 32 + 16 + lane] = ls1;
        }
        float* pb = pO + (size_t)slot * 4096 + (size_t)(G * 4) * DD + t;
#pragma unroll
        for (int u0 = 0; u0 < 8; ++u0) {
#pragma unroll
          for (int r = 0; r < 4; ++r) {
            pb[(size_t)r * DD + u0 * 16] = O[0][u0][r];
            pb[(size_t)(16 + r) * DD + u0 * 16] = O[1][u0][r];
          }
        }
      }
    }
    __syncthreads();   // protect cmb reuse by next visit
    m += cnt;
    ++sig;
  }
}

// ---- combine split tiles: sum <=4 partials, normalize, write out.
__global__ __launch_bounds__(256) void comb_kernel(const float* __restrict__ pO,
                                                   const float* __restrict__ pL,
                                                   float* __restrict__ out) {
  const int bi = blockIdx.x;          // 512: b = bi>>7, sig = bi&127
  const int b = bi >> 7, sig = bi & 127;
  const int tri = sig * (sig + 1) / 2;
  const int k0 = tri / 43, k1 = (tri + sig) / 43;
  const int parts = k1 - k0 + 1;
  if (parts == 1) return;             // handled directly by attn_kernel
  const int tid = threadIdx.x;
  const int q = tid >> 3, uc = (tid & 7) * 16;
  const int slot0 = (b * 128 + sig) * 4;

  float ls = 0.f;
  for (int p = 0; p < parts; ++p) ls += pL[(slot0 + p) * 32 + q];
  const float linv = 1.0f / ls;

  float4 acc[4] = {{0,0,0,0},{0,0,0,0},{0,0,0,0},{0,0,0,0}};
  for (int p = 0; p < parts; ++p) {
    const float* src = pO + (size_t)(slot0 + p) * 4096 + (size_t)q * DD + uc;
#pragma unroll
    for (int e = 0; e < 4; ++e) {
      float4 v = *reinterpret_cast<const float4*>(src + e * 4);
      acc[e].x += v.x; acc[e].y += v.y; acc[e].z += v.z; acc[e].w += v.w;
    }
  }
  float* dst = out + ((size_t)(b * T_SEQ + sig * 32 + q)) * DD + uc;
#pragma unroll
  for (int e = 0; e < 4; ++e) {
    acc[e].x *= linv; acc[e].y *= linv; acc[e].z *= linv; acc[e].w *= linv;
    *reinterpret_cast<float4*>(dst + e * 4) = acc[e];
  }
}

extern "C" void kernel_launch(void* const* d_in, const int* in_sizes, int n_in,
                              void* d_out, int out_size, void* d_ws, size_t ws_size,
                              hipStream_t stream) {
  const float* X  = (const float*)d_in[0];
  const float* Wq = (const float*)d_in[1];
  const float* Wk = (const float*)d_in[2];
  const float* Wv = (const float*)d_in[3];
  float* out = (float*)d_out;

  unsigned short* qf = (unsigned short*)d_ws;          // frag-major Q [BT/16][4][64][8]
  unsigned short* kf = qf + (size_t)BT * DD;            // frag-major K [BT/32][2][4][64][8]
  unsigned short* vt = kf + (size_t)BT * DD;            // k-blocked V^T [BT/32][128][32]
  unsigned short* fq = vt + (size_t)BT * DD;            // frag-major W (16384 each)
  unsigned short* fk = fq + DD * DD;
  unsigned short* fv = fk + DD * DD;
  float* pO = (float*)(fv + DD * DD);                   // partials [4*128*4][32][128]
  float* pL = pO + (size_t)4 * 128 * 4 * 32 * 128;      // partial rowsums [4*128*4][32]

  dim3 wt_grid(64, 3);
  wt_kernel<<<wt_grid, 256, 0, stream>>>(Wq, Wk, Wv, fq, fk, fv);
  proj_kernel<<<BT / 32, 256, 0, stream>>>(X, fq, fk, fv, qf, kf, vt);
  attn_kernel<<<768, 256, 0, stream>>>(qf, kf, vt, pO, pL, out);
  comb_kernel<<<512, 256, 0, stream>>>(pO, pL, out);
}

// Round 5
// 118.316 us; speedup vs baseline: 1.8718x; 1.2299x over previous
//
#include <hip/hip_runtime.h>

#define T_SEQ 4096
#define BATCH 4
#define DD 128
#define BT (BATCH * T_SEQ)

typedef __bf16 bf16x8 __attribute__((ext_vector_type(8)));
typedef float f32x4 __attribute__((ext_vector_type(4)));

__device__ inline bf16x8 ld8(const unsigned short* p) {
  return *reinterpret_cast<const bf16x8*>(p);
}
__device__ inline unsigned short bfc(float f) {
  __bf16 v = (__bf16)f;
  return __builtin_bit_cast(unsigned short, v);
}
__device__ inline float fexp2(float x) {
  float r;
  asm("v_exp_f32 %0, %1" : "=v"(r) : "v"(x));
  return r;
}

#define MFMA(a, b, c) __builtin_amdgcn_mfma_f32_16x16x32_bf16((a), (b), (c), 0, 0, 0)

// ---- W (128x128 f32, [d][u]) -> frag-major bf16:
// F[((n0*4+c)*64 + lane)*8 + j] = W[(c*32+g*8+j)*128 + n0*16+t], lane=(g<<4)|t.
__global__ void wt_kernel(const float* __restrict__ Wq, const float* __restrict__ Wk,
                          const float* __restrict__ Wv,
                          unsigned short* __restrict__ fq, unsigned short* __restrict__ fk,
                          unsigned short* __restrict__ fv) {
  const float* W = (blockIdx.y == 0) ? Wq : (blockIdx.y == 1) ? Wk : Wv;
  unsigned short* F = (blockIdx.y == 0) ? fq : (blockIdx.y == 1) ? fk : fv;
  int e = blockIdx.x * 256 + threadIdx.x;          // 0..16383
  int j = e & 7, lane = (e >> 3) & 63, nc = e >> 9;
  int c = nc & 3, n0 = nc >> 2;
  int t = lane & 15, g = lane >> 4;
  F[e] = bfc(W[(c * 32 + g * 8 + j) * 128 + n0 * 16 + t]);
}

// ---- projections, W-STATIONARY: wave w keeps W-frags for strips {w, w+4} in
// registers (24 KB loaded once/block) and streams 32 X-rows via LDS.
// qf folds (1/sqrt(4096)) * log2(e) so attn can use raw v_exp_f32 (2^x).
__global__ __launch_bounds__(256) void proj_kernel(
    const float* __restrict__ X,
    const unsigned short* __restrict__ fq,
    const unsigned short* __restrict__ fk,
    const unsigned short* __restrict__ fv,
    unsigned short* __restrict__ qf,
    unsigned short* __restrict__ kf,
    unsigned short* __restrict__ vt) {
  const int tid = threadIdx.x;
  const int w = tid >> 6, lane = tid & 63;
  const int t = lane & 15, g = lane >> 4;
  const int r0 = blockIdx.x * 32;   // 512 blocks x 32 rows

  __shared__ unsigned short xs[2][16 * 136];

  // resident W fragments: strips n0/u0 in {w, w+4}
  bf16x8 wq[2][4], wk[2][4], wv[2][4];
#pragma unroll
  for (int s = 0; s < 2; ++s)
#pragma unroll
    for (int c = 0; c < 4; ++c) {
      int fo = (((w + s * 4) * 4 + c) * 64 + lane) * 8;
      wq[s][c] = ld8(fq + fo);
      wk[s][c] = ld8(fk + fo);
      wv[s][c] = ld8(fv + fo);
    }

  // stage both 16-row X subtiles, coalesced
#pragma unroll
  for (int sub = 0; sub < 2; ++sub) {
    int r = tid >> 4, cb = tid & 15;
    const float* xp = X + (size_t)(r0 + sub * 16 + r) * DD + cb * 8;
    float4 lo = *reinterpret_cast<const float4*>(xp);
    float4 hi = *reinterpret_cast<const float4*>(xp + 4);
    bf16x8 tmp;
    tmp[0] = (__bf16)lo.x; tmp[1] = (__bf16)lo.y; tmp[2] = (__bf16)lo.z; tmp[3] = (__bf16)lo.w;
    tmp[4] = (__bf16)hi.x; tmp[5] = (__bf16)hi.y; tmp[6] = (__bf16)hi.z; tmp[7] = (__bf16)hi.w;
    *reinterpret_cast<bf16x8*>(&xs[sub][r * 136 + cb * 8]) = tmp;
  }
  __syncthreads();

#pragma unroll
  for (int sub = 0; sub < 2; ++sub) {
    const int r0s = r0 + sub * 16;
    bf16x8 x[4];
#pragma unroll
    for (int c = 0; c < 4; ++c)
      x[c] = ld8(&xs[sub][t * 136 + c * 32 + g * 8]);

    // Q, K strips
#pragma unroll
    for (int s = 0; s < 2; ++s) {
      const int n0 = w + s * 4;
      f32x4 aq = {0.f, 0.f, 0.f, 0.f}, ak = {0.f, 0.f, 0.f, 0.f};
#pragma unroll
      for (int c = 0; c < 4; ++c) {
        aq = MFMA(x[c], wq[s][c], aq);
        ak = MFMA(x[c], wk[s][c], ak);
      }
      const int cP = n0 >> 1;
      const int Gp = ((n0 & 1) << 1) | (t >> 3);
      const int ep = t & 7;
#pragma unroll
      for (int r = 0; r < 4; ++r) {
        int row = r0s + g * 4 + r;
        size_t qoff = ((size_t)((row >> 4) * 4 + cP) * 64 + ((Gp << 4) | (row & 15))) * 8 + ep;
        qf[qoff] = bfc(aq[r] * 0.0225421101f);   // (1/64) * log2(e)
        int tp = (row & 3) | (((row >> 3) & 3) << 2);
        size_t koff =
            ((size_t)(((row >> 5) * 2 + ((row >> 2) & 1)) * 4 + cP) * 64 + ((Gp << 4) | tp)) * 8 +
            ep;
        kf[koff] = bfc(ak[r]);
      }
    }

    // V strips (k-blocked V^T store)
    const int key = r0s + t;
    const size_t vbase = (size_t)(key >> 5) * 4096 + (key & 31);
#pragma unroll
    for (int s = 0; s < 2; ++s) {
      const int u0 = w + s * 4;
      f32x4 av = {0.f, 0.f, 0.f, 0.f};
#pragma unroll
      for (int c = 0; c < 4; ++c)
        av = MFMA(wv[s][c], x[c], av);
#pragma unroll
      for (int r = 0; r < 4; ++r)
        vt[vbase + (size_t)(u0 * 16 + g * 4 + r) * 32] = bfc(av[r]);
    }
  }
}

// ---- flash attention, uniform-work blocks: per batch the causal triangle's
// 8256 32-key chunks are flattened (tile sigma=0..127, chunk j=0..sigma) and
// cut into 192 blocks x EXACTLY 43 chunks (8256 = 192*43). Any 3 co-resident
// blocks give a CU exactly 129 chunks -> balance is dispatch-order-proof.
// launch_bounds(256,2): the round-0 proven compile point (112 VGPR) with the
// explicit K-prefetch across the backedge -- bounds(256,3) made the allocator
// pick an 84-reg serialized schedule (round-4 regression: VALUBusy 22->9).
// Combine LDS shrunk to 2 buffers (33.8 KB) so 4 blocks/CU fit: the whole
// 768-block grid is co-resident (3/CU avg, 12 waves/CU), zero drain tail.
// Blocks owning a whole tile normalize+store directly; boundary tiles write
// raw partial (O, l) to workspace slots and comb_kernel finishes them.
__global__ __launch_bounds__(256, 2) void attn_kernel(
    const unsigned short* __restrict__ qf,
    const unsigned short* __restrict__ kf,
    const unsigned short* __restrict__ vt,
    float* __restrict__ pO,
    float* __restrict__ pL,
    float* __restrict__ out) {
  const int tid = threadIdx.x;
  const int w = tid >> 6, lane = tid & 63;
  const int t = lane & 15, G = lane >> 4;
  const int bi = blockIdx.x;
  const int xcd = bi & 7;                      // assumed round-robin XCD mapping
  const int b = xcd >> 1;                      // batch pinned to an XCD pair (L2)
  const int k = ((bi >> 3) << 1) | (xcd & 1);  // 0..191 batch-local block index

  int m = k * 43;                              // global chunk range [m, mend)
  const int mend = m + 43;
  int sig = (int)(0.5f * (sqrtf(8.0f * (float)m + 1.0f) - 1.0f));
  while ((sig + 1) * (sig + 2) / 2 <= m) ++sig;
  while (sig * (sig + 1) / 2 > m) --sig;

  const unsigned short* kfb = kf + (size_t)b * (T_SEQ * DD);
  const unsigned short* vtb = vt + (size_t)b * (T_SEQ * DD);

  __shared__ float cmb[2][64][66];

  while (m < mend) {
    const int tri = sig * (sig + 1) / 2;
    const int j0 = m - tri;
    const int cnt = min(sig + 1 - j0, mend - m);
    const int q0 = sig * 32;
    const int jend = j0 + cnt;

    // Q fragments for tiles 2*sig, 2*sig+1
    bf16x8 qa[2][4];
#pragma unroll
    for (int p = 0; p < 2; ++p)
#pragma unroll
      for (int c = 0; c < 4; ++c)
        qa[p][c] = ld8(qf + ((size_t)((b * 256 + 2 * sig + p) * 4 + c) * 64 + lane) * 8);

    f32x4 O[2][8];
#pragma unroll
    for (int p = 0; p < 2; ++p)
#pragma unroll
      for (int u0 = 0; u0 < 8; ++u0) O[p][u0] = (f32x4){0.f, 0.f, 0.f, 0.f};
    float ls0 = 0.f, ls1 = 0.f;

    int j = j0 + w;
    bf16x8 kcur[8];
    if (j < jend) {
      const unsigned short* kblk = kfb + (size_t)j * 4096;
#pragma unroll
      for (int ci = 0; ci < 8; ++ci) kcur[ci] = ld8(kblk + ci * 512 + lane * 8);
    }

    for (; j < jend; j += 4) {
      // V frags for current chunk: issued first, consumed after QK+exp
      const unsigned short* vblk = vtb + (size_t)j * 4096;
      bf16x8 vcur[8];
#pragma unroll
      for (int u0 = 0; u0 < 8; ++u0) vcur[u0] = ld8(vblk + (u0 * 16 + t) * 32 + G * 8);
      // prefetch next chunk's K across the backedge
      bf16x8 knxt[8];
      if (j + 4 < jend) {
        const unsigned short* kb2 = kfb + (size_t)(j + 4) * 4096;
#pragma unroll
        for (int ci = 0; ci < 8; ++ci) knxt[ci] = ld8(kb2 + ci * 512 + lane * 8);
      }

      f32x4 s00 = {0.f, 0.f, 0.f, 0.f}, s01 = {0.f, 0.f, 0.f, 0.f};
      f32x4 s10 = {0.f, 0.f, 0.f, 0.f}, s11 = {0.f, 0.f, 0.f, 0.f};
#pragma unroll
      for (int c = 0; c < 4; ++c) {
        s00 = MFMA(kcur[c], qa[0][c], s00);
        s01 = MFMA(kcur[4 + c], qa[0][c], s01);
        s10 = MFMA(kcur[c], qa[1][c], s10);
        s11 = MFMA(kcur[4 + c], qa[1][c], s11);
      }

      bf16x8 pb0, pb1;
      if (j < sig) {
        // fully-unmasked chunk (all but the diagonal): no causal compares
#pragma unroll
        for (int r = 0; r < 4; ++r) {
          float e00 = fexp2(s00[r]), e01 = fexp2(s01[r]);
          float e10 = fexp2(s10[r]), e11 = fexp2(s11[r]);
          ls0 += e00 + e01;
          ls1 += e10 + e11;
          pb0[r] = (__bf16)e00; pb0[r + 4] = (__bf16)e01;
          pb1[r] = (__bf16)e10; pb1[r + 4] = (__bf16)e11;
        }
      } else {
#pragma unroll
        for (int r = 0; r < 4; ++r) {
          int k0 = j * 32 + G * 8 + r;
          float e00 = (k0 <= q0 + t) ? fexp2(s00[r]) : 0.f;
          float e01 = (k0 + 4 <= q0 + t) ? fexp2(s01[r]) : 0.f;
          float e10 = (k0 <= q0 + 16 + t) ? fexp2(s10[r]) : 0.f;
          float e11 = (k0 + 4 <= q0 + 16 + t) ? fexp2(s11[r]) : 0.f;
          ls0 += e00 + e01;
          ls1 += e10 + e11;
          pb0[r] = (__bf16)e00; pb0[r + 4] = (__bf16)e01;
          pb1[r] = (__bf16)e10; pb1[r + 4] = (__bf16)e11;
        }
      }

#pragma unroll
      for (int u0 = 0; u0 < 8; ++u0) {
        O[0][u0] = MFMA(pb0, vcur[u0], O[0][u0]);
        O[1][u0] = MFMA(pb1, vcur[u0], O[1][u0]);
      }
#pragma unroll
      for (int ci = 0; ci < 8; ++ci) kcur[ci] = knxt[ci];
    }

    // ---- 4-wave combine via 2-buffer LDS tree
    auto publish = [&](int buf) {
#pragma unroll
      for (int p = 0; p < 2; ++p)
#pragma unroll
        for (int u0 = 0; u0 < 8; ++u0)
          *reinterpret_cast<f32x4*>(&cmb[buf][lane][p * 32 + u0 * 4]) = O[p][u0];
      cmb[buf][lane][64] = ls0;
      cmb[buf][lane][65] = ls1;
    };
    auto absorb = [&](int buf) {
#pragma unroll
      for (int p = 0; p < 2; ++p)
#pragma unroll
        for (int u0 = 0; u0 < 8; ++u0) {
          f32x4 q4 = *reinterpret_cast<const f32x4*>(&cmb[buf][lane][p * 32 + u0 * 4]);
          O[p][u0][0] += q4[0]; O[p][u0][1] += q4[1];
          O[p][u0][2] += q4[2]; O[p][u0][3] += q4[3];
        }
      ls0 += cmb[buf][lane][64];
      ls1 += cmb[buf][lane][65];
    };
    // stage A: waves 1,3 publish; waves 0,2 absorb -> owners {0+1, 2+3}
    if (w == 1) publish(0);
    if (w == 3) publish(1);
    __syncthreads();
    if (w == 0) absorb(0);
    if (w == 2) absorb(1);
    __syncthreads();
    // stage B: wave 2 publishes; wave 0 absorbs all
    if (w == 2) publish(0);
    __syncthreads();

    if (w == 0) {
      absorb(0);
      // row sums over G-groups: afterwards each lane holds the rowsum for
      // query (lane&15) of its tile half
      ls0 += __shfl_xor(ls0, 16); ls0 += __shfl_xor(ls0, 32);
      ls1 += __shfl_xor(ls1, 16); ls1 += __shfl_xor(ls1, 32);

      if (j0 == 0 && cnt == sig + 1) {
        // whole tile in this block: normalize and store directly
        float linv0[4], linv1[4];
#pragma unroll
        for (int r = 0; r < 4; ++r) {
          linv0[r] = 1.0f / __shfl(ls0, G * 4 + r);
          linv1[r] = 1.0f / __shfl(ls1, G * 4 + r);
        }
        float* op0 = out + ((size_t)(b * T_SEQ + q0 + G * 4)) * DD + t;
        float* op1 = op0 + (size_t)16 * DD;
#pragma unroll
        for (int u0 = 0; u0 < 8; ++u0) {
#pragma unroll
          for (int r = 0; r < 4; ++r) {
            op0[(size_t)r * DD + u0 * 16] = O[0][u0][r] * linv0[r];
            op1[(size_t)r * DD + u0 * 16] = O[1][u0][r] * linv1[r];
          }
        }
      } else {
        // partial: raw sums to workspace slot (part = k - first block of tile)
        const int part = k - tri / 43;
        const int slot = (b * 128 + sig) * 4 + part;
        if (lane < 16) {
          pL[slot * 32 + lane] = ls0;
          pL[slot * 32 + 16 + lane] = ls1;
        }
        float* pb = pO + (size_t)slot * 4096 + (size_t)(G * 4) * DD + t;
#pragma unroll
        for (int u0 = 0; u0 < 8; ++u0) {
#pragma unroll
          for (int r = 0; r < 4; ++r) {
            pb[(size_t)r * DD + u0 * 16] = O[0][u0][r];
            pb[(size_t)(16 + r) * DD + u0 * 16] = O[1][u0][r];
          }
        }
      }
    }
    __syncthreads();   // protect cmb reuse by next visit
    m += cnt;
    ++sig;
  }
}

// ---- combine split tiles: sum <=4 partials, normalize, write out.
__global__ __launch_bounds__(256) void comb_kernel(const float* __restrict__ pO,
                                                   const float* __restrict__ pL,
                                                   float* __restrict__ out) {
  const int bi = blockIdx.x;          // 512: b = bi>>7, sig = bi&127
  const int b = bi >> 7, sig = bi & 127;
  const int tri = sig * (sig + 1) / 2;
  const int k0 = tri / 43, k1 = (tri + sig) / 43;
  const int parts = k1 - k0 + 1;
  if (parts == 1) return;             // handled directly by attn_kernel
  const int tid = threadIdx.x;
  const int q = tid >> 3, uc = (tid & 7) * 16;
  const int slot0 = (b * 128 + sig) * 4;

  float ls = 0.f;
  for (int p = 0; p < parts; ++p) ls += pL[(slot0 + p) * 32 + q];
  const float linv = 1.0f / ls;

  float4 acc[4] = {{0,0,0,0},{0,0,0,0},{0,0,0,0},{0,0,0,0}};
  for (int p = 0; p < parts; ++p) {
    const float* src = pO + (size_t)(slot0 + p) * 4096 + (size_t)q * DD + uc;
#pragma unroll
    for (int e = 0; e < 4; ++e) {
      float4 v = *reinterpret_cast<const float4*>(src + e * 4);
      acc[e].x += v.x; acc[e].y += v.y; acc[e].z += v.z; acc[e].w += v.w;
    }
  }
  float* dst = out + ((size_t)(b * T_SEQ + sig * 32 + q)) * DD + uc;
#pragma unroll
  for (int e = 0; e < 4; ++e) {
    acc[e].x *= linv; acc[e].y *= linv; acc[e].z *= linv; acc[e].w *= linv;
    *reinterpret_cast<float4*>(dst + e * 4) = acc[e];
  }
}

extern "C" void kernel_launch(void* const* d_in, const int* in_sizes, int n_in,
                              void* d_out, int out_size, void* d_ws, size_t ws_size,
                              hipStream_t stream) {
  const float* X  = (const float*)d_in[0];
  const float* Wq = (const float*)d_in[1];
  const float* Wk = (const float*)d_in[2];
  const float* Wv = (const float*)d_in[3];
  float* out = (float*)d_out;

  unsigned short* qf = (unsigned short*)d_ws;          // frag-major Q [BT/16][4][64][8]
  unsigned short* kf = qf + (size_t)BT * DD;            // frag-major K [BT/32][2][4][64][8]
  unsigned short* vt = kf + (size_t)BT * DD;            // k-blocked V^T [BT/32][128][32]
  unsigned short* fq = vt + (size_t)BT * DD;            // frag-major W (16384 each)
  unsigned short* fk = fq + DD * DD;
  unsigned short* fv = fk + DD * DD;
  float* pO = (float*)(fv + DD * DD);                   // partials [4*128*4][32][128]
  float* pL = pO + (size_t)4 * 128 * 4 * 32 * 128;      // partial rowsums [4*128*4][32]

  dim3 wt_grid(64, 3);
  wt_kernel<<<wt_grid, 256, 0, stream>>>(Wq, Wk, Wv, fq, fk, fv);
  proj_kernel<<<BT / 32, 256, 0, stream>>>(X, fq, fk, fv, qf, kf, vt);
  attn_kernel<<<768, 256, 0, stream>>>(qf, kf, vt, pO, pL, out);
  comb_kernel<<<512, 256, 0, stream>>>(pO, pL, out);
}

// Round 7
// 114.799 us; speedup vs baseline: 1.9291x; 1.0306x over previous
//
#include <hip/hip_runtime.h>

#define T_SEQ 4096
#define BATCH 4
#define DD 128
#define BT (BATCH * T_SEQ)
#define CPB 12            // chunks per attn block: 2112 = 176 * 12 exactly
#define KPB 176           // blocks per batch
#define MAXPARTS 12

typedef __bf16 bf16x8 __attribute__((ext_vector_type(8)));
typedef float f32x4 __attribute__((ext_vector_type(4)));

__device__ inline bf16x8 ld8(const unsigned short* p) {
  return *reinterpret_cast<const bf16x8*>(p);
}
__device__ inline unsigned short bfc(float f) {
  __bf16 v = (__bf16)f;
  return __builtin_bit_cast(unsigned short, v);
}
__device__ inline float fexp2(float x) {
  float r;
  asm("v_exp_f32 %0, %1" : "=v"(r) : "v"(x));
  return r;
}
// V-buffer swizzle: XOR the 16B slot (bits 3-4 of the short index) with
// (row>>1)&3 so 16 lanes reading different rows at one column hit 8 distinct
// bank quads (residual 2-way aliasing is free). Row = 32 shorts = 64 B.
__device__ inline int vsw(int sIdx) {
  return sIdx ^ ((((sIdx >> 6) & 3) << 3));   // row = sIdx>>5; (row>>1)&3 = (sIdx>>6)&3
}

#define MFMA(a, b, c) __builtin_amdgcn_mfma_f32_16x16x32_bf16((a), (b), (c), 0, 0, 0)

// ---- W (128x128 f32, [d][u]) -> frag-major bf16:
// F[((n0*4+c)*64 + lane)*8 + j] = W[(c*32+g*8+j)*128 + n0*16+t], lane=(g<<4)|t.
__global__ void wt_kernel(const float* __restrict__ Wq, const float* __restrict__ Wk,
                          const float* __restrict__ Wv,
                          unsigned short* __restrict__ fq, unsigned short* __restrict__ fk,
                          unsigned short* __restrict__ fv) {
  const float* W = (blockIdx.y == 0) ? Wq : (blockIdx.y == 1) ? Wk : Wv;
  unsigned short* F = (blockIdx.y == 0) ? fq : (blockIdx.y == 1) ? fk : fv;
  int e = blockIdx.x * 256 + threadIdx.x;          // 0..16383
  int j = e & 7, lane = (e >> 3) & 63, nc = e >> 9;
  int c = nc & 3, n0 = nc >> 2;
  int t = lane & 15, g = lane >> 4;
  F[e] = bfc(W[(c * 32 + g * 8 + j) * 128 + n0 * 16 + t]);
}

// ---- projections, W-STATIONARY (unchanged, proven). qf folds (1/64)*log2(e).
__global__ __launch_bounds__(256) void proj_kernel(
    const float* __restrict__ X,
    const unsigned short* __restrict__ fq,
    const unsigned short* __restrict__ fk,
    const unsigned short* __restrict__ fv,
    unsigned short* __restrict__ qf,
    unsigned short* __restrict__ kf,
    unsigned short* __restrict__ vt) {
  const int tid = threadIdx.x;
  const int w = tid >> 6, lane = tid & 63;
  const int t = lane & 15, g = lane >> 4;
  const int r0 = blockIdx.x * 32;   // 512 blocks x 32 rows

  __shared__ unsigned short xs[2][16 * 136];

  bf16x8 wq[2][4], wk[2][4], wv[2][4];
#pragma unroll
  for (int s = 0; s < 2; ++s)
#pragma unroll
    for (int c = 0; c < 4; ++c) {
      int fo = (((w + s * 4) * 4 + c) * 64 + lane) * 8;
      wq[s][c] = ld8(fq + fo);
      wk[s][c] = ld8(fk + fo);
      wv[s][c] = ld8(fv + fo);
    }

#pragma unroll
  for (int sub = 0; sub < 2; ++sub) {
    int r = tid >> 4, cb = tid & 15;
    const float* xp = X + (size_t)(r0 + sub * 16 + r) * DD + cb * 8;
    float4 lo = *reinterpret_cast<const float4*>(xp);
    float4 hi = *reinterpret_cast<const float4*>(xp + 4);
    bf16x8 tmp;
    tmp[0] = (__bf16)lo.x; tmp[1] = (__bf16)lo.y; tmp[2] = (__bf16)lo.z; tmp[3] = (__bf16)lo.w;
    tmp[4] = (__bf16)hi.x; tmp[5] = (__bf16)hi.y; tmp[6] = (__bf16)hi.z; tmp[7] = (__bf16)hi.w;
    *reinterpret_cast<bf16x8*>(&xs[sub][r * 136 + cb * 8]) = tmp;
  }
  __syncthreads();

#pragma unroll
  for (int sub = 0; sub < 2; ++sub) {
    const int r0s = r0 + sub * 16;
    bf16x8 x[4];
#pragma unroll
    for (int c = 0; c < 4; ++c)
      x[c] = ld8(&xs[sub][t * 136 + c * 32 + g * 8]);

#pragma unroll
    for (int s = 0; s < 2; ++s) {
      const int n0 = w + s * 4;
      f32x4 aq = {0.f, 0.f, 0.f, 0.f}, ak = {0.f, 0.f, 0.f, 0.f};
#pragma unroll
      for (int c = 0; c < 4; ++c) {
        aq = MFMA(x[c], wq[s][c], aq);
        ak = MFMA(x[c], wk[s][c], ak);
      }
      const int cP = n0 >> 1;
      const int Gp = ((n0 & 1) << 1) | (t >> 3);
      const int ep = t & 7;
#pragma unroll
      for (int r = 0; r < 4; ++r) {
        int row = r0s + g * 4 + r;
        size_t qoff = ((size_t)((row >> 4) * 4 + cP) * 64 + ((Gp << 4) | (row & 15))) * 8 + ep;
        qf[qoff] = bfc(aq[r] * 0.0225421101f);   // (1/64) * log2(e)
        int tp = (row & 3) | (((row >> 3) & 3) << 2);
        size_t koff =
            ((size_t)(((row >> 5) * 2 + ((row >> 2) & 1)) * 4 + cP) * 64 + ((Gp << 4) | tp)) * 8 +
            ep;
        kf[koff] = bfc(ak[r]);
      }
    }

    const int key = r0s + t;
    const size_t vbase = (size_t)(key >> 5) * 4096 + (key & 31);
#pragma unroll
    for (int s = 0; s < 2; ++s) {
      const int u0 = w + s * 4;
      f32x4 av = {0.f, 0.f, 0.f, 0.f};
#pragma unroll
      for (int c = 0; c < 4; ++c)
        av = MFMA(wv[s][c], x[c], av);
#pragma unroll
      for (int r = 0; r < 4; ++r)
        vt[vbase + (size_t)(u0 * 16 + g * 4 + r) * 32] = bfc(av[r]);
    }
  }
}

// ---- flash attention, LDS-shared K/V: a block's 4 waves process the SAME
// 32-key chunk for 4 different 32-query tiles (a 128-row q-group: tiles
// 4*sg..4*sg+3, wave w owns tile 4*sg+w). Per chunk the block stages 16 KB
// (K 8KB + V 8KB) ONCE: reg-staged T14 split -- global loads issued at iter
// top, ds_write after compute, double-buffered, one __syncthreads per chunk.
// L2 traffic drops 4x vs per-wave loads and L2 latency leaves the critical
// path (ds_read ~12cy). bufV is slot-XOR swizzled (vsw) so the PV read
// (different rows, same column) is conflict-free; bufK stays linear
// (lane-linear reads). No inter-wave combine (waves own disjoint queries).
// Work flattened per batch: sum over groups sg=0..31 of (4sg+4) chunks =
// 2112 = 176 blocks x 12; any co-resident blocks are balanced. Split groups
// write per-wave raw partials (<=12 parts); comb_kernel finishes them.
__global__ __launch_bounds__(256, 2) void attn_kernel(
    const unsigned short* __restrict__ qf,
    const unsigned short* __restrict__ kf,
    const unsigned short* __restrict__ vt,
    float* __restrict__ pO,
    float* __restrict__ pL,
    float* __restrict__ out) {
  const int tid = threadIdx.x;
  const int w = tid >> 6, lane = tid & 63;
  const int t = lane & 15, G = lane >> 4;
  const int bi = blockIdx.x;
  const int xcd = bi & 7;                      // assumed round-robin XCD mapping
  const int b = xcd >> 1;                      // batch pinned to an XCD pair (L2)
  const int k = ((bi >> 3) << 1) | (xcd & 1);  // 0..175 batch-local block index

  const int m0 = k * CPB, mend = m0 + CPB;
  // decode flat chunk index -> (group sg, chunk j); cum(sg) = 2*sg*(sg+1)
  int sg = (int)(0.5f * (sqrtf(1.0f + 2.0f * (float)m0) - 1.0f));
  while (2 * (sg + 1) * (sg + 2) <= m0) ++sg;
  while (2 * sg * (sg + 1) > m0) --sg;
  int j = m0 - 2 * sg * (sg + 1);

  const unsigned short* kfb = kf + (size_t)b * (T_SEQ * DD);
  const unsigned short* vtb = vt + (size_t)b * (T_SEQ * DD);

  __shared__ unsigned short bufK[2][4096], bufV[2][4096];

  // ---- prologue: stage chunk j into buf 0 (16KB: each thread 4 x 16B)
  bf16x8 st0, st1, st2, st3;
  {
    const unsigned short* kch = kfb + (size_t)j * 4096;
    const unsigned short* vch = vtb + (size_t)j * 4096;
    st0 = ld8(kch + tid * 8);
    st1 = ld8(kch + 2048 + tid * 8);
    st2 = ld8(vch + tid * 8);
    st3 = ld8(vch + 2048 + tid * 8);
    *reinterpret_cast<bf16x8*>(&bufK[0][tid * 8]) = st0;
    *reinterpret_cast<bf16x8*>(&bufK[0][2048 + tid * 8]) = st1;
    *reinterpret_cast<bf16x8*>(&bufV[0][vsw(tid * 8)]) = st2;
    *reinterpret_cast<bf16x8*>(&bufV[0][vsw(2048 + tid * 8)]) = st3;
  }
  __syncthreads();

  // staging-stream key for chunk m+1
  int sgS = sg, jS = j + 1;
  if (jS == 4 * sgS + 4) { ++sgS; jS = 0; }

  bf16x8 qa[2][4];
  f32x4 O[2][8];
  float ls0 = 0.f, ls1 = 0.f;
  bool fresh = true;
  int jbeg = j;
  int cur = 0;

  for (int m = m0; m < mend; ++m) {
    const int sig32 = 4 * sg + w;        // this wave's 32-row tile index
    const int q0 = sig32 * 32;

    if (fresh) {
#pragma unroll
      for (int p = 0; p < 2; ++p)
#pragma unroll
        for (int c = 0; c < 4; ++c)
          qa[p][c] = ld8(qf + ((size_t)((b * 256 + 2 * sig32 + p) * 4 + c) * 64 + lane) * 8);
#pragma unroll
      for (int p = 0; p < 2; ++p)
#pragma unroll
        for (int u0 = 0; u0 < 8; ++u0) O[p][u0] = (f32x4){0.f, 0.f, 0.f, 0.f};
      ls0 = 0.f; ls1 = 0.f;
      jbeg = j;
      fresh = false;
    }

    // issue next-chunk stage loads (consumed by ds_write after compute)
    const bool more = (m + 1 < mend);
    if (more) {
      const unsigned short* kch = kfb + (size_t)jS * 4096;
      const unsigned short* vch = vtb + (size_t)jS * 4096;
      st0 = ld8(kch + tid * 8);
      st1 = ld8(kch + 2048 + tid * 8);
      st2 = ld8(vch + tid * 8);
      st3 = ld8(vch + 2048 + tid * 8);
    }

    // ---- compute chunk j from LDS (skip if fully masked for this wave)
    if (j <= sig32) {
      f32x4 s00 = {0.f, 0.f, 0.f, 0.f}, s01 = {0.f, 0.f, 0.f, 0.f};
      f32x4 s10 = {0.f, 0.f, 0.f, 0.f}, s11 = {0.f, 0.f, 0.f, 0.f};
      {
        bf16x8 kc[4];
#pragma unroll
        for (int c = 0; c < 4; ++c) kc[c] = ld8(&bufK[cur][c * 512 + lane * 8]);
#pragma unroll
        for (int c = 0; c < 4; ++c) {
          s00 = MFMA(kc[c], qa[0][c], s00);
          s10 = MFMA(kc[c], qa[1][c], s10);
        }
#pragma unroll
        for (int c = 0; c < 4; ++c) kc[c] = ld8(&bufK[cur][(4 + c) * 512 + lane * 8]);
#pragma unroll
        for (int c = 0; c < 4; ++c) {
          s01 = MFMA(kc[c], qa[0][c], s01);
          s11 = MFMA(kc[c], qa[1][c], s11);
        }
      }

      bf16x8 pb0, pb1;
      if (j < sig32) {
        // fully-unmasked chunk: no causal compares
#pragma unroll
        for (int r = 0; r < 4; ++r) {
          float e00 = fexp2(s00[r]), e01 = fexp2(s01[r]);
          float e10 = fexp2(s10[r]), e11 = fexp2(s11[r]);
          ls0 += e00 + e01;
          ls1 += e10 + e11;
          pb0[r] = (__bf16)e00; pb0[r + 4] = (__bf16)e01;
          pb1[r] = (__bf16)e10; pb1[r + 4] = (__bf16)e11;
        }
      } else {
        // diagonal chunk (j == sig32)
#pragma unroll
        for (int r = 0; r < 4; ++r) {
          int k0 = j * 32 + G * 8 + r;
          float e00 = (k0 <= q0 + t) ? fexp2(s00[r]) : 0.f;
          float e01 = (k0 + 4 <= q0 + t) ? fexp2(s01[r]) : 0.f;
          float e10 = (k0 <= q0 + 16 + t) ? fexp2(s10[r]) : 0.f;
          float e11 = (k0 + 4 <= q0 + 16 + t) ? fexp2(s11[r]) : 0.f;
          ls0 += e00 + e01;
          ls1 += e10 + e11;
          pb0[r] = (__bf16)e00; pb0[r + 4] = (__bf16)e01;
          pb1[r] = (__bf16)e10; pb1[r + 4] = (__bf16)e11;
        }
      }

#pragma unroll
      for (int u0 = 0; u0 < 8; ++u0) {
        bf16x8 vcu = ld8(&bufV[cur][vsw((u0 * 16 + t) * 32 + G * 8)]);
        O[0][u0] = MFMA(pb0, vcu, O[0][u0]);
        O[1][u0] = MFMA(pb1, vcu, O[1][u0]);
      }
    }

    // ---- flush at group end or block end (block-uniform condition)
    const bool gend = (j == 4 * sg + 3);
    if (gend || m == mend - 1) {
      float r0s = ls0; r0s += __shfl_xor(r0s, 16); r0s += __shfl_xor(r0s, 32);
      float r1s = ls1; r1s += __shfl_xor(r1s, 16); r1s += __shfl_xor(r1s, 32);
      if (jbeg == 0 && gend) {
        // whole group in this block: each wave normalizes + stores its tile
        float linv0[4], linv1[4];
#pragma unroll
        for (int r = 0; r < 4; ++r) {
          linv0[r] = 1.0f / __shfl(r0s, G * 4 + r);
          linv1[r] = 1.0f / __shfl(r1s, G * 4 + r);
        }
        float* op0 = out + ((size_t)(b * T_SEQ + q0 + G * 4)) * DD + t;
        float* op1 = op0 + (size_t)16 * DD;
#pragma unroll
        for (int u0 = 0; u0 < 8; ++u0) {
#pragma unroll
          for (int r = 0; r < 4; ++r) {
            op0[(size_t)r * DD + u0 * 16] = O[0][u0][r] * linv0[r];
            op1[(size_t)r * DD + u0 * 16] = O[1][u0][r] * linv1[r];
          }
        }
      } else {
        // split group: raw per-wave partial to workspace
        const int part = k - (2 * sg * (sg + 1)) / CPB;
        const int slot = (b * 128 + sig32) * MAXPARTS + part;
        if (lane < 16) {
          pL[slot * 32 + lane] = r0s;
          pL[slot * 32 + 16 + lane] = r1s;
        }
        float* pb = pO + (size_t)slot * 4096 + (size_t)(G * 4) * DD + t;
#pragma unroll
        for (int u0 = 0; u0 < 8; ++u0) {
#pragma unroll
          for (int r = 0; r < 4; ++r) {
            pb[(size_t)r * DD + u0 * 16] = O[0][u0][r];
            pb[(size_t)(16 + r) * DD + u0 * 16] = O[1][u0][r];
          }
        }
      }
      fresh = true;   // next chunk (if any) starts a new group
    }

    // ---- write staged chunk m+1 into the other buffer, then barrier
    if (more) {
      const int nxt = cur ^ 1;
      *reinterpret_cast<bf16x8*>(&bufK[nxt][tid * 8]) = st0;
      *reinterpret_cast<bf16x8*>(&bufK[nxt][2048 + tid * 8]) = st1;
      *reinterpret_cast<bf16x8*>(&bufV[nxt][vsw(tid * 8)]) = st2;
      *reinterpret_cast<bf16x8*>(&bufV[nxt][vsw(2048 + tid * 8)]) = st3;
    }
    __syncthreads();
    cur ^= 1;

    // advance compute key and stage key
    ++j;
    if (j == 4 * sg + 4) { ++sg; j = 0; }
    if (more) {
      ++jS;
      if (jS == 4 * sgS + 4) { ++sgS; jS = 0; }
    }
  }
}

// ---- combine split groups: sum <=12 per-wave partials, normalize, store.
__global__ __launch_bounds__(256) void comb_kernel(const float* __restrict__ pO,
                                                   const float* __restrict__ pL,
                                                   float* __restrict__ out) {
  const int bi = blockIdx.x;          // 512: b = bi>>7, sig32 = bi&127
  const int b = bi >> 7, sig32 = bi & 127;
  const int sg = sig32 >> 2;
  const int cum = 2 * sg * (sg + 1);
  const int n = 4 * sg + 4;
  const int kfirst = cum / CPB, klast = (cum + n - 1) / CPB;
  const int parts = klast - kfirst + 1;
  if (parts == 1) return;             // handled directly by attn_kernel
  const int tid = threadIdx.x;
  const int q = tid >> 3, uc = (tid & 7) * 16;
  const int slot0 = (b * 128 + sig32) * MAXPARTS;

  float ls = 0.f;
  for (int p = 0; p < parts; ++p) ls += pL[(slot0 + p) * 32 + q];
  const float linv = 1.0f / ls;

  float4 acc[4] = {{0,0,0,0},{0,0,0,0},{0,0,0,0},{0,0,0,0}};
  for (int p = 0; p < parts; ++p) {
    const float* src = pO + (size_t)(slot0 + p) * 4096 + (size_t)q * DD + uc;
#pragma unroll
    for (int e = 0; e < 4; ++e) {
      float4 v = *reinterpret_cast<const float4*>(src + e * 4);
      acc[e].x += v.x; acc[e].y += v.y; acc[e].z += v.z; acc[e].w += v.w;
    }
  }
  float* dst = out + ((size_t)(b * T_SEQ + sig32 * 32 + q)) * DD + uc;
#pragma unroll
  for (int e = 0; e < 4; ++e) {
    acc[e].x *= linv; acc[e].y *= linv; acc[e].z *= linv; acc[e].w *= linv;
    *reinterpret_cast<float4*>(dst + e * 4) = acc[e];
  }
}

extern "C" void kernel_launch(void* const* d_in, const int* in_sizes, int n_in,
                              void* d_out, int out_size, void* d_ws, size_t ws_size,
                              hipStream_t stream) {
  const float* X  = (const float*)d_in[0];
  const float* Wq = (const float*)d_in[1];
  const float* Wk = (const float*)d_in[2];
  const float* Wv = (const float*)d_in[3];
  float* out = (float*)d_out;

  unsigned short* qf = (unsigned short*)d_ws;          // frag-major Q [BT/16][4][64][8]
  unsigned short* kf = qf + (size_t)BT * DD;            // frag-major K [BT/32][2][4][64][8]
  unsigned short* vt = kf + (size_t)BT * DD;            // k-blocked V^T [BT/32][128][32]
  unsigned short* fq = vt + (size_t)BT * DD;            // frag-major W (16384 each)
  unsigned short* fk = fq + DD * DD;
  unsigned short* fv = fk + DD * DD;
  float* pO = (float*)(fv + DD * DD);                   // partials [4*128*12][32][128]
  float* pL = pO + (size_t)BATCH * 128 * MAXPARTS * 32 * 128;  // rowsums [...][32]

  dim3 wt_grid(64, 3);
  wt_kernel<<<wt_grid, 256, 0, stream>>>(Wq, Wk, Wv, fq, fk, fv);
  proj_kernel<<<BT / 32, 256, 0, stream>>>(X, fq, fk, fv, qf, kf, vt);
  attn_kernel<<<BATCH * KPB, 256, 0, stream>>>(qf, kf, vt, pO, pL, out);
  comb_kernel<<<512, 256, 0, stream>>>(pO, pL, out);
}